// Round 1
// baseline (68.411 us; speedup 1.0000x reference)
//
#include <hip/hip_runtime.h>
#include <hip/hip_bf16.h>

// SchattenSimilarityLoss: loss = mean_b (out_b - label_b)^2 where
//   out_b = ||A B^T||_F / ( sqrt(||A A^T||_F) * sqrt(||B B^T||_F) )
// Only Frobenius sums of the three S x S products are needed -> MFMA
// gemm-BT tiles with on-the-fly square-accumulate, never materializing M.

typedef __attribute__((ext_vector_type(8)))  short short8;   // 8 bf16 (4 VGPRs)
typedef __attribute__((ext_vector_type(16))) float f32x16;   // 32x32 MFMA acc

constexpr int BATCH = 128;
constexpr int S     = 256;
constexpr int D     = 384;
constexpr int BK    = 64;          // K slice per LDS stage
constexpr int NK    = D / BK;      // 6
constexpr int TILE  = 128;         // per-WG output tile is TILE x TILE

__device__ __forceinline__ short bf16_of(float f) {
    __hip_bfloat16 h = __float2bfloat16(f);   // RNE
    short s;
    __builtin_memcpy(&s, &h, 2);
    return s;
}

__device__ __forceinline__ short8 pack_bf16x8(float4 a, float4 b) {
    short8 r;
    r[0] = bf16_of(a.x); r[1] = bf16_of(a.y); r[2] = bf16_of(a.z); r[3] = bf16_of(a.w);
    r[4] = bf16_of(b.x); r[5] = bf16_of(b.y); r[6] = bf16_of(b.z); r[7] = bf16_of(b.w);
    return r;
}

// One WG computes sum of squares of a 128x128 tile of X Y^T for one batch,
// where (X,Y) is one of (A,B), (A,A), (B,B). Partial written to ws[blockIdx.x].
__global__ __launch_bounds__(256, 2)
void gram_tiles(const float* __restrict__ A, const float* __restrict__ Bm,
                float* __restrict__ ws)
{
    __shared__ short lx[TILE * BK];   // 16 KiB, bf16, XOR-swizzled 16B chunks
    __shared__ short ly[TILE * BK];   // 16 KiB
    __shared__ float red[256];

    const int wg    = blockIdx.x;
    const int batch = wg / 12;
    const int r     = wg % 12;
    const int p     = r >> 2;          // 0: A*B^T  1: A*A^T  2: B*B^T
    const int tr    = (r >> 1) & 1;    // tile row block (rows of X)
    const int tc    = r & 1;           // tile col block (rows of Y)

    const size_t base = (size_t)batch * S * D;
    const float* X = (p == 2 ? Bm : A) + base + (size_t)tr * TILE * D;
    const float* Y = (p == 1 ? A  : Bm) + base + (size_t)tc * TILE * D;

    const int tid  = threadIdx.x;
    const int lane = tid & 63;
    const int w    = tid >> 6;         // wave 0..3, arranged 2x2
    const int wr   = w >> 1, wc = w & 1;

    f32x16 acc00 = {}, acc01 = {}, acc10 = {}, acc11 = {};

    const int arow  = wr * 64 + (lane & 31);   // fr=0 row; fr=1 adds 32
    const int brow  = wc * 64 + (lane & 31);
    const int khalf = lane >> 5;               // k-half within 16B-chunk pair

    for (int kt = 0; kt < NK; ++kt) {
        // ---- stage X,Y K-slice -> LDS bf16 (16B chunks, chunk ^= row&7) ----
        #pragma unroll
        for (int i = 0; i < 4; ++i) {
            const int c   = i * 256 + tid;     // chunk id 0..1023
            const int row = c >> 3;            // 0..127
            const int ch  = c & 7;             // 16B chunk within row
            const float* gx = X + row * D + kt * BK + ch * 8;
            const float* gy = Y + row * D + kt * BK + ch * 8;
            float4 x0 = *(const float4*)gx;
            float4 x1 = *(const float4*)(gx + 4);
            float4 y0 = *(const float4*)gy;
            float4 y1 = *(const float4*)(gy + 4);
            const int dst = row * BK + ((ch ^ (row & 7)) << 3);
            *(short8*)&lx[dst] = pack_bf16x8(x0, x1);
            *(short8*)&ly[dst] = pack_bf16x8(y0, y1);
        }
        __syncthreads();

        // ---- MFMA: 4 frags (2x2 of 32x32) x 4 k-substeps of 16 ----
        #pragma unroll
        for (int kk = 0; kk < 4; ++kk) {
            const int ch  = kk * 2 + khalf;           // 16B chunk index in row
            const int ra0 = arow,      ra1 = arow + 32;
            const int rb0 = brow,      rb1 = brow + 32;
            short8 a0 = *(const short8*)&lx[ra0 * BK + ((ch ^ (ra0 & 7)) << 3)];
            short8 a1 = *(const short8*)&lx[ra1 * BK + ((ch ^ (ra1 & 7)) << 3)];
            short8 b0 = *(const short8*)&ly[rb0 * BK + ((ch ^ (rb0 & 7)) << 3)];
            short8 b1 = *(const short8*)&ly[rb1 * BK + ((ch ^ (rb1 & 7)) << 3)];
            acc00 = __builtin_amdgcn_mfma_f32_32x32x16_bf16(a0, b0, acc00, 0, 0, 0);
            acc01 = __builtin_amdgcn_mfma_f32_32x32x16_bf16(a0, b1, acc01, 0, 0, 0);
            acc10 = __builtin_amdgcn_mfma_f32_32x32x16_bf16(a1, b0, acc10, 0, 0, 0);
            acc11 = __builtin_amdgcn_mfma_f32_32x32x16_bf16(a1, b1, acc11, 0, 0, 0);
        }
        __syncthreads();
    }

    // ---- sum of squares of this WG's tile ----
    float s = 0.f;
    #pragma unroll
    for (int i = 0; i < 16; ++i) {
        s += acc00[i] * acc00[i];
        s += acc01[i] * acc01[i];
        s += acc10[i] * acc10[i];
        s += acc11[i] * acc11[i];
    }
    red[tid] = s;
    __syncthreads();
    for (int off = 128; off > 0; off >>= 1) {
        if (tid < off) red[tid] += red[tid + off];
        __syncthreads();
    }
    if (tid == 0) ws[wg] = red[0];
}

// Combine 12 partials per batch -> per-batch output -> MSE loss (scalar).
__global__ void finalize(const float* __restrict__ ws,
                         const float* __restrict__ labels,
                         float* __restrict__ out)
{
    __shared__ float red[128];
    const int t = threadIdx.x;      // 128 threads, one per batch
    const float* wb = ws + t * 12;
    float s_ab = 0.f, s_aa = 0.f, s_bb = 0.f;
    #pragma unroll
    for (int i = 0; i < 4; ++i) {
        s_ab += wb[i];
        s_aa += wb[4 + i];
        s_bb += wb[8 + i];
    }
    const float cross  = sqrtf(s_ab);
    const float norm_a = sqrtf(sqrtf(s_aa));
    const float norm_b = sqrtf(sqrtf(s_bb));
    const float outb   = cross / (norm_a * norm_b);
    const float d      = outb - labels[t];
    red[t] = d * d * (1.0f / 128.0f);
    __syncthreads();
    for (int off = 64; off > 0; off >>= 1) {
        if (t < off) red[t] += red[t + off];
        __syncthreads();
    }
    if (t == 0) out[0] = red[0];
}

extern "C" void kernel_launch(void* const* d_in, const int* in_sizes, int n_in,
                              void* d_out, int out_size, void* d_ws, size_t ws_size,
                              hipStream_t stream)
{
    const float* A      = (const float*)d_in[0];
    const float* Bm     = (const float*)d_in[1];
    const float* labels = (const float*)d_in[2];
    float* ws = (float*)d_ws;   // 1536 floats, every slot written each launch

    gram_tiles<<<dim3(BATCH * 12), dim3(256), 0, stream>>>(A, Bm, ws);
    finalize<<<dim3(1), dim3(128), 0, stream>>>(ws, labels, (float*)d_out);
}

// Round 2
// 33.486 us; speedup vs baseline: 2.0430x; 2.0430x over previous
//
#include <hip/hip_runtime.h>
#include <hip/hip_bf16.h>

// loss = mean_b (out_b - label_b)^2,
// out_b = sqrt(s_ab) / (s_aa^(1/4) * s_bb^(1/4)),
// s_xy  = sum_{s,t} (X_s . Y_t)^2  (Frobenius^2 of X Y^T).
//
// 4 WGs per batch, each stages a stack of 128-row blocks (full K inside WG,
// double-buffered BK=64 chunks) and computes several 128x128 tile-products
// from the shared stack, square-accumulating into one scalar:
//   type0: stack {A0,A1}   -> AA tiles (0,0),(0,1)x2,(1,1)      -> s_aa
//   type1: stack {B0,B1}   -> BB tiles                           -> s_bb
//   type2: stack {A0,B0,B1}-> AB tiles (A0,B0),(A0,B1)           -> s_ab
//   type3: stack {A1,B0,B1}-> AB tiles (A1,B0),(A1,B1)           -> s_ab

typedef short  short8  __attribute__((ext_vector_type(8)));
typedef short  short4_ __attribute__((ext_vector_type(4)));
typedef float  f32x16  __attribute__((ext_vector_type(16)));

constexpr int BATCH = 128;
constexpr int S     = 256;
constexpr int D     = 384;
constexpr int BK    = 64;        // K per LDS chunk
constexpr int NCH   = D / BK;    // 6 chunks
constexpr int ROWS  = 384;       // LDS stack rows (max over types)

// Job tables: [tt][wave][slot] = {xu, yu, w}; xu/yu are 64-row units in the
// stack; w=0 -> slot unused. tt=0: aa/bb (10 jobs), tt=1: ab (8 jobs).
__device__ const signed char JT[2][8][2][3] = {
  { // tt=0: units 0,1 = block0; 2,3 = block1
    {{0,0,1},{1,2,2}}, {{0,1,2},{1,3,2}}, {{1,1,1},{0,0,0}}, {{2,2,1},{0,0,0}},
    {{2,3,2},{0,0,0}}, {{3,3,1},{0,0,0}}, {{0,2,2},{0,0,0}}, {{0,3,2},{0,0,0}}
  },
  { // tt=1: units 0,1 = A-block; 2,3 = B0; 4,5 = B1
    {{0,2,1},{0,0,0}}, {{0,3,1},{0,0,0}}, {{1,2,1},{0,0,0}}, {{1,3,1},{0,0,0}},
    {{0,4,1},{0,0,0}}, {{0,5,1},{0,0,0}}, {{1,4,1},{0,0,0}}, {{1,5,1},{0,0,0}}
  }
};

__device__ __forceinline__ short bf16_of(float f) {
    __hip_bfloat16 h = __float2bfloat16(f);
    short s; __builtin_memcpy(&s, &h, 2); return s;
}

// Pack 8 f32 -> 8 bf16; swap 4-element halves when row is odd (the 8B-granular
// XOR-16 swizzle maps logical subchunks (2ch, 2ch+1) of odd rows in reversed
// order within their 16B slot).
__device__ __forceinline__ short8 pack8(float4 a, float4 b, bool swap) {
    short s0=bf16_of(a.x), s1=bf16_of(a.y), s2=bf16_of(a.z), s3=bf16_of(a.w);
    short s4=bf16_of(b.x), s5=bf16_of(b.y), s6=bf16_of(b.z), s7=bf16_of(b.w);
    short8 r;
    if (!swap) { r[0]=s0;r[1]=s1;r[2]=s2;r[3]=s3;r[4]=s4;r[5]=s5;r[6]=s6;r[7]=s7; }
    else       { r[0]=s4;r[1]=s5;r[2]=s6;r[3]=s7;r[4]=s0;r[5]=s1;r[6]=s2;r[7]=s3; }
    return r;
}

// Read one MFMA operand fragment (8 bf16) for `row`, k-step `ks`, as two b64
// reads at 8B-swizzled positions: logical subchunk u at position u ^ (row&15).
// 16 slots x XOR-16 -> 2-way bank aliasing only (free).
__device__ __forceinline__ short8 frag_read(const short* L, int row, int ks, int lane) {
    const int u0 = (ks * 2 + (lane >> 5)) * 2;   // logical 8B subchunk base
    const int x  = row & 15;
    const int rb = row * BK;
    short8 f;
    *(short4_*)&f       = *(const short4_*)&L[rb + ((u0    ) ^ x) * 4];
    ((short4_*)&f)[1]   = *(const short4_*)&L[rb + ((u0 + 1) ^ x) * 4];
    return f;
}

#define MFMA(a,b,c) __builtin_amdgcn_mfma_f32_32x32x16_bf16(a, b, c, 0, 0, 0)

__global__ __launch_bounds__(512, 2)
void gram(const float* __restrict__ A, const float* __restrict__ B,
          float* __restrict__ ws)
{
    __shared__ short lds[2][ROWS * BK];   // 2 x 48 KiB

    // bid -> (xcd, batch, type): all 4 WGs of a batch land on one XCD and are
    // launched adjacently -> staged blocks shared via that XCD's L2.
    const int bid  = blockIdx.x;
    const int xcd  = bid & 7;
    const int idx  = bid >> 3;
    const int batch= xcd * 16 + (idx >> 2);
    const int type = idx & 3;
    const int tt   = type >> 1;

    const float* Ab = A + (size_t)batch * S * D;
    const float* Bb = B + (size_t)batch * S * D;

    const int tid  = threadIdx.x;
    const int lane = tid & 63;
    const int wv   = tid >> 6;
    const int l31  = lane & 31;

    const int nit = tt ? 6 : 4;   // stage iterations: 384 vs 256 rows

    // per-wave jobs (wave-uniform scalars)
    const int  xu0 = JT[tt][wv][0][0], yu0 = JT[tt][wv][0][1];
    const float w0 = (float)JT[tt][wv][0][2];
    const int  xu1 = JT[tt][wv][1][0], yu1 = JT[tt][wv][1][1];
    const int  w1i = JT[tt][wv][1][2];
    const bool has2 = (w1i != 0);
    const float w1 = (float)w1i;

    f32x16 a00={}, a01={}, a10={}, a11={};
    f32x16 c00={}, c01={}, c10={}, c11={};

    float4 v0[6], v1[6];

    // ---- staging helpers (unrolled, static reg indices) ----
    #define STAGE_LOAD(kc)                                                     \
        _Pragma("unroll") for (int i = 0; i < 6; ++i) if (i < nit) {           \
            const int c_  = i * 512 + tid;                                     \
            const int row = c_ >> 3, ch = c_ & 7;                              \
            const float* sp; int sr;                                           \
            if (tt == 0)        { sp = (type == 0) ? Ab : Bb; sr = row; }      \
            else if (row < 128) { sp = Ab; sr = (type == 3) ? row + 128 : row;}\
            else                { sp = Bb; sr = row - 128; }                   \
            const float* p = sp + sr * D + (kc) * BK + ch * 8;                 \
            v0[i] = *(const float4*)p; v1[i] = *(const float4*)(p + 4);        \
        }

    #define STAGE_WRITE(bsel)                                                  \
        _Pragma("unroll") for (int i = 0; i < 6; ++i) if (i < nit) {           \
            const int c_  = i * 512 + tid;                                     \
            const int row = c_ >> 3, ch = c_ & 7;                              \
            const int slot = ch ^ ((row >> 1) & 7);                            \
            *(short8*)&lds[bsel][row * BK + slot * 8] =                        \
                pack8(v0[i], v1[i], (row & 1) != 0);                           \
        }

    auto compute = [&](const short* L) {
        #pragma unroll
        for (int ks = 0; ks < 4; ++ks) {
            short8 xa0 = frag_read(L, xu0 * 64 + l31,      ks, lane);
            short8 xa1 = frag_read(L, xu0 * 64 + l31 + 32, ks, lane);
            short8 yb0 = frag_read(L, yu0 * 64 + l31,      ks, lane);
            short8 yb1 = frag_read(L, yu0 * 64 + l31 + 32, ks, lane);
            a00 = MFMA(xa0, yb0, a00); a01 = MFMA(xa0, yb1, a01);
            a10 = MFMA(xa1, yb0, a10); a11 = MFMA(xa1, yb1, a11);
            if (has2) {
                short8 xc0 = frag_read(L, xu1 * 64 + l31,      ks, lane);
                short8 xc1 = frag_read(L, xu1 * 64 + l31 + 32, ks, lane);
                short8 yd0 = frag_read(L, yu1 * 64 + l31,      ks, lane);
                short8 yd1 = frag_read(L, yu1 * 64 + l31 + 32, ks, lane);
                c00 = MFMA(xc0, yd0, c00); c01 = MFMA(xc0, yd1, c01);
                c10 = MFMA(xc1, yd0, c10); c11 = MFMA(xc1, yd1, c11);
            }
        }
    };

    // ---- main loop: prefetch chunk c+1 while computing chunk c ----
    STAGE_LOAD(0);
    STAGE_WRITE(0);
    __syncthreads();
    for (int c = 0; c < NCH; ++c) {
        if (c + 1 < NCH) STAGE_LOAD(c + 1);        // issue early (T14)
        compute(lds[c & 1]);
        if (c + 1 < NCH) STAGE_WRITE((c + 1) & 1); // vmcnt wait lands here
        __syncthreads();
    }

    // ---- square-accumulate + WG reduction -> one scalar ----
    float sum = 0.f;
    #pragma unroll
    for (int i = 0; i < 16; ++i)
        sum += a00[i]*a00[i] + a01[i]*a01[i] + a10[i]*a10[i] + a11[i]*a11[i];
    sum *= w0;
    if (has2) {
        float s1 = 0.f;
        #pragma unroll
        for (int i = 0; i < 16; ++i)
            s1 += c00[i]*c00[i] + c01[i]*c01[i] + c10[i]*c10[i] + c11[i]*c11[i];
        sum += w1 * s1;
    }
    #pragma unroll
    for (int o = 32; o > 0; o >>= 1) sum += __shfl_xor(sum, o, 64);
    float* red = (float*)lds;
    if (lane == 0) red[wv] = sum;
    __syncthreads();
    if (tid == 0) {
        float t = 0.f;
        #pragma unroll
        for (int i = 0; i < 8; ++i) t += red[i];
        ws[bid] = t;
    }
}

__global__ void finalize(const float* __restrict__ ws,
                         const float* __restrict__ labels,
                         float* __restrict__ out)
{
    __shared__ float red[128];
    const int t = threadIdx.x;            // one thread per batch
    const int xcd = t >> 4, loc = t & 15;
    const int s0 = ((loc * 4 + 0) << 3) | xcd;
    const int s1 = ((loc * 4 + 1) << 3) | xcd;
    const int s2 = ((loc * 4 + 2) << 3) | xcd;
    const int s3 = ((loc * 4 + 3) << 3) | xcd;
    const float s_aa = ws[s0];
    const float s_bb = ws[s1];
    const float s_ab = ws[s2] + ws[s3];
    const float outb = sqrtf(s_ab) / (sqrtf(sqrtf(s_aa)) * sqrtf(sqrtf(s_bb)));
    const float d    = outb - labels[t];
    red[t] = d * d * (1.0f / 128.0f);
    __syncthreads();
    for (int off = 64; off > 0; off >>= 1) {
        if (t < off) red[t] += red[t + off];
        __syncthreads();
    }
    if (t == 0) out[0] = red[0];
}

extern "C" void kernel_launch(void* const* d_in, const int* in_sizes, int n_in,
                              void* d_out, int out_size, void* d_ws, size_t ws_size,
                              hipStream_t stream)
{
    const float* A      = (const float*)d_in[0];
    const float* B      = (const float*)d_in[1];
    const float* labels = (const float*)d_in[2];
    float* ws = (float*)d_ws;   // 512 floats, all written every launch

    gram<<<dim3(BATCH * 4), dim3(512), 0, stream>>>(A, B, ws);
    finalize<<<dim3(1), dim3(128), 0, stream>>>(ws, labels, (float*)d_out);
}